// Round 1
// baseline (141.670 us; speedup 1.0000x reference)
//
#include <hip/hip_runtime.h>

// Problem constants (from reference)
#define VOCABN 256
#define DN 512
#define MN 4
#define DSN 2
#define KN 5
#define BN 8
#define LN 8192
#define WN 24                    // window positions per block (multiple of lcm(2,3,4)=12)
#define NWN ((LN + WN - 1) / WN) // 342 windows per batch
#define LOUTN (LN / DSN)         // 4096

// ---------------- kernel 1: repack conv_w [O][I][K] -> Wt [K][I][O] ----------------
__global__ void repack_kernel(const float* __restrict__ cw, float* __restrict__ Wt) {
  int idx = blockIdx.x * 256 + threadIdx.x;
  if (idx < KN * DN * DN) {
    int o = idx % DN;
    int i = (idx / DN) % DN;
    int k = idx / (DN * DN);
    Wt[idx] = cw[(o * DN + i) * KN + k];
  }
}

// ---------------- kernel 2: partial GEMM ----------------
// Gp[ic][k][v][o] = sum_{i in chunk ic} emb[v][i] * Wt[k][i][o]
// grid.x = (VOCABN/4) * nic, block = 512 threads (thread <-> o)
__global__ __launch_bounds__(512) void gpart_kernel(const float* __restrict__ emb,
                                                    const float* __restrict__ Wt,
                                                    float* __restrict__ Gp, int clen) {
  const int o = threadIdx.x;
  const int vg = blockIdx.x % (VOCABN / 4);
  const int ic = blockIdx.x / (VOCABN / 4);
  __shared__ float se[4 * 512];  // up to 4 rows x clen(<=512)
  for (int t = threadIdx.x; t < 4 * clen; t += 512) {
    int v = t / clen, i = t % clen;
    se[v * clen + i] = emb[(vg * 4 + v) * DN + ic * clen + i];
  }
  __syncthreads();
  float acc[4][KN];
#pragma unroll
  for (int v = 0; v < 4; ++v)
#pragma unroll
    for (int k = 0; k < KN; ++k) acc[v][k] = 0.f;

  for (int i = 0; i < clen; ++i) {
    const int ig = ic * clen + i;
    float wv[KN];
#pragma unroll
    for (int k = 0; k < KN; ++k) wv[k] = Wt[(k * DN + ig) * DN + o];
#pragma unroll
    for (int v = 0; v < 4; ++v) {
      const float e = se[v * clen + i];
#pragma unroll
      for (int k = 0; k < KN; ++k) acc[v][k] += e * wv[k];
    }
  }
#pragma unroll
  for (int v = 0; v < 4; ++v)
#pragma unroll
    for (int k = 0; k < KN; ++k)
      Gp[((size_t)(ic * KN + k) * VOCABN + (vg * 4 + v)) * DN + o] = acc[v][k];
}

// ---------------- kernel 3: reduce partials -> G[k][v][o] ----------------
__global__ void greduce_kernel(const float* __restrict__ Gp, float* __restrict__ G, int nic) {
  int e = blockIdx.x * 256 + threadIdx.x;
  if (e < KN * VOCABN * DN) {
    float s = 0.f;
    for (int ic = 0; ic < nic; ++ic) s += Gp[(size_t)ic * (KN * VOCABN * DN) + e];
    G[e] = s;
  }
}

// ---------------- kernel 4: fused GBST main ----------------
// block = (batch, 24-position window), 512 threads (thread <-> channel o)
__global__ __launch_bounds__(512) void gbst_main_kernel(const int* __restrict__ ids,
                                                        const float* __restrict__ G,
                                                        const float* __restrict__ conv_b,
                                                        const float* __restrict__ score_w,
                                                        float* __restrict__ out) {
  const int blk = blockIdx.x;
  const int b = blk / NWN;
  const int w = blk % NWN;
  const int l0 = w * WN;
  const int tid = threadIdx.x;
  const int o = tid;
  const int wave = tid >> 6;
  const int lane = tid & 63;

  __shared__ int s_ids[WN + 4];
  __shared__ float sred[8][WN];
  __shared__ float t_s[WN];
  __shared__ float wm_s[WN][MN];

  if (tid < WN + 4) {
    int p = l0 - 2 + tid;
    s_ids[tid] = (p >= 0 && p < LN) ? ids[b * LN + p] : -1;
  }
  __syncthreads();

  const float bias = conv_b[o];
  const float sw = score_w[o];

  // conv output y[s][o] via G-table gathers; zero for s beyond L (pooling zero-pad)
  float y[WN];
#pragma unroll
  for (int s = 0; s < WN; ++s) {
    float acc = 0.f;
    if (l0 + s < LN) {
      acc = bias;
#pragma unroll
      for (int k = 0; k < KN; ++k) {
        int v = s_ids[s + k];
        if (v >= 0) acc += G[(size_t)(k * VOCABN + v) * DN + o];
      }
    }
    y[s] = acc;
  }

  // t[s] = sum_o y[s][o] * score_w[o]  (block-wide reduction over o)
#pragma unroll
  for (int s = 0; s < WN; ++s) {
    float v = y[s] * sw;
#pragma unroll
    for (int off = 32; off > 0; off >>= 1) v += __shfl_xor(v, off, 64);
    if (lane == 0) sred[wave][s] = v;
  }
  __syncthreads();
  if (tid < WN) {
    float sum = 0.f;
#pragma unroll
    for (int q = 0; q < 8; ++q) sum += sred[q][tid];
    t_s[tid] = sum;
  }
  __syncthreads();

  // per-position softmax over the 4 block-size scores
  if (tid < WN && l0 + tid < LN) {
    const int ll = tid;
    float s1 = t_s[ll];
    int j2 = ll & ~1;
    float s2 = 0.5f * (t_s[j2] + t_s[j2 + 1]);
    int j3 = (ll / 3) * 3;
    float s3 = (1.f / 3.f) * (t_s[j3] + t_s[j3 + 1] + t_s[j3 + 2]);
    int j4 = ll & ~3;
    float s4 = 0.25f * (t_s[j4] + t_s[j4 + 1] + t_s[j4 + 2] + t_s[j4 + 3]);
    float mx = fmaxf(fmaxf(s1, s2), fmaxf(s3, s4));
    float e1 = __expf(s1 - mx), e2 = __expf(s2 - mx);
    float e3 = __expf(s3 - mx), e4 = __expf(s4 - mx);
    float inv = 1.f / (e1 + e2 + e3 + e4);
    wm_s[ll][0] = e1 * inv;
    wm_s[ll][1] = e2 * inv;
    wm_s[ll][2] = e3 * inv;
    wm_s[ll][3] = e4 * inv;
  }
  __syncthreads();

  // register block sums (all indices compile-time after unroll)
  float S2[12], S3[8], S4[6];
#pragma unroll
  for (int j = 0; j < 12; ++j) S2[j] = y[2 * j] + y[2 * j + 1];
#pragma unroll
  for (int j = 0; j < 8; ++j) S3[j] = y[3 * j] + y[3 * j + 1] + y[3 * j + 2];
#pragma unroll
  for (int j = 0; j < 6; ++j) S4[j] = S2[2 * j] + S2[2 * j + 1];

  // latent mix + final /2 downsample, write coalesced
#pragma unroll
  for (int jo = 0; jo < WN / 2; ++jo) {
    const int orow = (l0 >> 1) + jo;
    if (orow < LOUTN) {
      float acc = 0.f;
#pragma unroll
      for (int dl = 0; dl < 2; ++dl) {
        const int ll = 2 * jo + dl;
        acc += wm_s[ll][0] * y[ll];
        acc += wm_s[ll][1] * (0.5f * S2[ll >> 1]);
        acc += wm_s[ll][2] * ((1.f / 3.f) * S3[ll / 3]);
        acc += wm_s[ll][3] * (0.25f * S4[ll >> 2]);
      }
      out[((size_t)b * LOUTN + orow) * DN + o] = 0.5f * acc;
    }
  }
}

extern "C" void kernel_launch(void* const* d_in, const int* in_sizes, int n_in,
                              void* d_out, int out_size, void* d_ws, size_t ws_size,
                              hipStream_t stream) {
  const int* ids = (const int*)d_in[0];
  const float* emb = (const float*)d_in[1];
  const float* conv_w = (const float*)d_in[2];
  const float* conv_b = (const float*)d_in[3];
  const float* score_w = (const float*)d_in[4];
  float* out = (float*)d_out;

  const size_t WT_BYTES = (size_t)KN * DN * DN * 4;          // 5.24 MB
  const size_t G_BYTES = (size_t)KN * VOCABN * DN * 4;       // 2.62 MB
  // choose split-K factor based on available workspace
  int nic = 8;
  if (ws_size < WT_BYTES + (size_t)8 * G_BYTES + G_BYTES) nic = 1;

  char* ws = (char*)d_ws;
  float* Wt = (float*)ws;
  float* Gp = (float*)(ws + WT_BYTES);
  float* G = (float*)(ws + WT_BYTES + (size_t)nic * G_BYTES);
  if (nic == 1) Gp = G;  // write partials directly as final

  repack_kernel<<<dim3((KN * DN * DN + 255) / 256), dim3(256), 0, stream>>>(conv_w, Wt);
  gpart_kernel<<<dim3((VOCABN / 4) * nic), dim3(512), 0, stream>>>(emb, Wt, Gp, DN / nic);
  if (nic > 1)
    greduce_kernel<<<dim3((KN * VOCABN * DN + 255) / 256), dim3(256), 0, stream>>>(Gp, G, nic);
  gbst_main_kernel<<<dim3(BN * NWN), dim3(512), 0, stream>>>(ids, G, conv_b, score_w, out);
}

// Round 2
// 122.793 us; speedup vs baseline: 1.1537x; 1.1537x over previous
//
#include <hip/hip_runtime.h>

#define VOCABN 256
#define DN 512
#define MN 4
#define DSN 2
#define KN 5
#define BN 8
#define LN 8192
#define WN 24                    // window positions per block (multiple of lcm(2,3,4)=12)
#define NWN ((LN + WN - 1) / WN) // 342 windows per batch
#define LOUTN (LN / DSN)         // 4096
#define NROWS (KN * VOCABN)      // 1280 G rows (+1 zero row)
#define ROWB (DN * 4)            // 2048 bytes per G row
#define VPB 8                    // vocab rows per gpart block

// ---------------- kernel 1: repack conv_w [O][I][K] -> Wt [K][I][O] ----------------
__global__ void repack_kernel(const float* __restrict__ cw, float* __restrict__ Wt) {
  int idx = blockIdx.x * 256 + threadIdx.x;
  if (idx < KN * DN * DN) {
    int o = idx % DN;
    int i = (idx / DN) % DN;
    int k = idx / (DN * DN);
    Wt[idx] = cw[(o * DN + i) * KN + k];
  }
}

// ---------------- kernel 2: partial GEMM ----------------
// Gp[ic][k][v][o] = sum_{i in chunk ic} emb[v][i] * Wt[k][i][o]
__global__ __launch_bounds__(512) void gpart_kernel(const float* __restrict__ emb,
                                                    const float* __restrict__ Wt,
                                                    float* __restrict__ Gp, int clen) {
  const int o = threadIdx.x;
  const int vg = blockIdx.x % (VOCABN / VPB);
  const int ic = blockIdx.x / (VOCABN / VPB);
  __shared__ float se[VPB * DN];
  for (int t = threadIdx.x; t < VPB * clen; t += 512) {
    int v = t / clen, i = t % clen;
    se[v * clen + i] = emb[(vg * VPB + v) * DN + ic * clen + i];
  }
  __syncthreads();
  float acc[VPB][KN];
#pragma unroll
  for (int v = 0; v < VPB; ++v)
#pragma unroll
    for (int k = 0; k < KN; ++k) acc[v][k] = 0.f;

  for (int i = 0; i < clen; ++i) {
    const int ig = ic * clen + i;
    float wv[KN];
#pragma unroll
    for (int k = 0; k < KN; ++k) wv[k] = Wt[(k * DN + ig) * DN + o];
#pragma unroll
    for (int v = 0; v < VPB; ++v) {
      const float e = se[v * clen + i];
#pragma unroll
      for (int k = 0; k < KN; ++k) acc[v][k] += e * wv[k];
    }
  }
#pragma unroll
  for (int v = 0; v < VPB; ++v)
#pragma unroll
    for (int k = 0; k < KN; ++k)
      Gp[((size_t)(ic * KN + k) * VOCABN + (vg * VPB + v)) * DN + o] = acc[v][k];
}

// ---------------- kernel 3: reduce partials -> G[k][v][o] ----------------
__global__ void greduce_kernel(const float* __restrict__ Gp, float* __restrict__ G, int nic) {
  int e = blockIdx.x * 256 + threadIdx.x;
  if (e < NROWS * DN) {
    float s = 0.f;
    for (int ic = 0; ic < nic; ++ic) s += Gp[(size_t)ic * (NROWS * DN) + e];
    G[e] = s;
  }
}

// ---------------- kernel 4: score table SW[row] = G[row]·score_w, zero row, sbias ----------------
// grid = NROWS + 2 blocks of 64 threads.
//   block r < NROWS : SW[r] = sum_o G[r][o]*score_w[o]
//   block NROWS     : G[NROWS][o] = 0 (zero row), SW[NROWS] = 0
//   block NROWS+1   : SW[NROWS+1] = sum_o conv_b[o]*score_w[o]  (sbias)
__global__ __launch_bounds__(64) void swtab_kernel(const float* __restrict__ G,
                                                   const float* __restrict__ conv_b,
                                                   const float* __restrict__ score_w,
                                                   float* __restrict__ Gz,
                                                   float* __restrict__ SW) {
  const int r = blockIdx.x;
  const int lane = threadIdx.x;
  if (r == NROWS) {
#pragma unroll
    for (int q = 0; q < DN / 64; ++q) Gz[(size_t)NROWS * DN + lane + q * 64] = 0.f;
    if (lane == 0) SW[NROWS] = 0.f;
    return;
  }
  const float* src = (r == NROWS + 1) ? conv_b : (G + (size_t)r * DN);
  float acc = 0.f;
#pragma unroll
  for (int q = 0; q < DN / 64; ++q) acc += src[lane + q * 64] * score_w[lane + q * 64];
#pragma unroll
  for (int off = 32; off > 0; off >>= 1) acc += __shfl_xor(acc, off, 64);
  if (lane == 0) SW[r] = acc;
}

// ---------------- kernel 5: fused GBST main ----------------
// block = (batch, 24-position window), 256 threads, thread <-> channel pair (float2)
__global__ __launch_bounds__(256) void gbst_main_kernel(const int* __restrict__ ids,
                                                        const float* __restrict__ G,
                                                        const float* __restrict__ SW,
                                                        const float* __restrict__ conv_b,
                                                        float* __restrict__ out) {
  const int blk = blockIdx.x;
  const int b = blk / NWN;
  const int w = blk % NWN;
  const int l0 = w * WN;
  const int tid = threadIdx.x;

  __shared__ int offs[WN + 4][KN];  // byte offset of G row for tap (j,k)
  __shared__ float t_s[WN];
  __shared__ float4 wm_s[WN];

  // P0: per-tap row offsets (zero row for out-of-range)
  if (tid < (WN + 4) * KN) {
    int j = tid / KN, k = tid % KN;
    int p = l0 + j - 2;
    int row = NROWS;
    if ((unsigned)p < (unsigned)LN) row = k * VOCABN + ids[b * LN + p];
    offs[j][k] = row * ROWB;
  }
  __syncthreads();

  // P3 (issued early): gather conv outputs y[s] = conv_b + sum_k G[k][id], float2 per thread
  const char* Gb = (const char*)G;
  const int laneoff = tid * 8;
  const float2 bias = *(const float2*)(conv_b + 2 * tid);
  float2 y[WN];
#pragma unroll
  for (int s = 0; s < WN; ++s) {
    float2 acc;
    acc.x = 0.f;
    acc.y = 0.f;
#pragma unroll
    for (int k = 0; k < KN; ++k) {
      const float2 g = *(const float2*)(Gb + offs[s + k][k] + laneoff);
      acc.x += g.x;
      acc.y += g.y;
    }
    bool valid = (l0 + s) < LN;
    y[s].x = valid ? acc.x + bias.x : 0.f;
    y[s].y = valid ? acc.y + bias.y : 0.f;
  }

  // P1: scalar scores t[s] via SW table (threads 0..23)
  if (tid < WN) {
    float tv = 0.f;
    if (l0 + tid < LN) {
      tv = SW[NROWS + 1];  // sbias
#pragma unroll
      for (int k = 0; k < KN; ++k) tv += SW[offs[tid + k][k] >> 11];
    }
    t_s[tid] = tv;
  }
  __syncthreads();

  // P2: per-position softmax over the 4 block-size scores (threads 0..23)
  if (tid < WN && l0 + tid < LN) {
    const int ll = tid;
    float s1 = t_s[ll];
    int j2 = ll & ~1;
    float s2 = 0.5f * (t_s[j2] + t_s[j2 + 1]);
    int j3 = (ll / 3) * 3;
    float s3 = (1.f / 3.f) * (t_s[j3] + t_s[j3 + 1] + t_s[j3 + 2]);
    int j4 = ll & ~3;
    float s4 = 0.25f * (t_s[j4] + t_s[j4 + 1] + t_s[j4 + 2] + t_s[j4 + 3]);
    float mx = fmaxf(fmaxf(s1, s2), fmaxf(s3, s4));
    float e1 = __expf(s1 - mx), e2 = __expf(s2 - mx);
    float e3 = __expf(s3 - mx), e4 = __expf(s4 - mx);
    float inv = 1.f / (e1 + e2 + e3 + e4);
    wm_s[ll] = make_float4(e1 * inv, e2 * inv, e3 * inv, e4 * inv);
  }
  __syncthreads();

  // block sums (compile-time indices)
  float2 S2[12], S3[8], S4[6];
#pragma unroll
  for (int j = 0; j < 12; ++j) {
    S2[j].x = y[2 * j].x + y[2 * j + 1].x;
    S2[j].y = y[2 * j].y + y[2 * j + 1].y;
  }
#pragma unroll
  for (int j = 0; j < 8; ++j) {
    S3[j].x = y[3 * j].x + y[3 * j + 1].x + y[3 * j + 2].x;
    S3[j].y = y[3 * j].y + y[3 * j + 1].y + y[3 * j + 2].y;
  }
#pragma unroll
  for (int j = 0; j < 6; ++j) {
    S4[j].x = S2[2 * j].x + S2[2 * j + 1].x;
    S4[j].y = S2[2 * j].y + S2[2 * j + 1].y;
  }

  // latent mix + final /2 downsample, coalesced float2 stores
#pragma unroll
  for (int jo = 0; jo < WN / 2; ++jo) {
    const int orow = (l0 >> 1) + jo;
    if (orow < LOUTN) {
      float2 acc;
      acc.x = 0.f;
      acc.y = 0.f;
#pragma unroll
      for (int dl = 0; dl < 2; ++dl) {
        const int ll = 2 * jo + dl;
        const float4 wv = wm_s[ll];
        const float c2 = wv.y * 0.5f;
        const float c3 = wv.z * (1.f / 3.f);
        const float c4 = wv.w * 0.25f;
        acc.x += wv.x * y[ll].x + c2 * S2[jo].x + c3 * S3[ll / 3].x + c4 * S4[jo >> 1].x;
        acc.y += wv.x * y[ll].y + c2 * S2[jo].y + c3 * S3[ll / 3].y + c4 * S4[jo >> 1].y;
      }
      float2 o2;
      o2.x = 0.5f * acc.x;
      o2.y = 0.5f * acc.y;
      *(float2*)(out + ((size_t)b * LOUTN + orow) * DN + 2 * tid) = o2;
    }
  }
}

extern "C" void kernel_launch(void* const* d_in, const int* in_sizes, int n_in,
                              void* d_out, int out_size, void* d_ws, size_t ws_size,
                              hipStream_t stream) {
  const int* ids = (const int*)d_in[0];
  const float* emb = (const float*)d_in[1];
  const float* conv_w = (const float*)d_in[2];
  const float* conv_b = (const float*)d_in[3];
  const float* score_w = (const float*)d_in[4];
  float* out = (float*)d_out;

  const size_t WT_BYTES = (size_t)KN * DN * DN * 4;            // 5.24 MB
  const size_t GP_BYTES = (size_t)NROWS * DN * 4;              // 2.62 MB per partial
  const size_t G_BYTES = (size_t)(NROWS + 1) * DN * 4;         // G + zero row
  const size_t SW_BYTES = (size_t)(NROWS + 2) * 4;             // SW + zero + sbias

  int nic = 8;
  if (ws_size < WT_BYTES + 8 * GP_BYTES + G_BYTES + SW_BYTES) nic = 1;

  char* ws = (char*)d_ws;
  float* Wt = (float*)ws;
  float* Gp = (float*)(ws + WT_BYTES);
  float* G = (float*)(ws + WT_BYTES + (size_t)nic * GP_BYTES);
  if (nic == 1) {
    Gp = (float*)(ws + WT_BYTES);
    G = Gp;  // write directly as final
  }
  float* SW = (float*)((char*)G + G_BYTES);

  repack_kernel<<<dim3((KN * DN * DN + 255) / 256), dim3(256), 0, stream>>>(conv_w, Wt);
  gpart_kernel<<<dim3((VOCABN / VPB) * nic), dim3(512), 0, stream>>>(emb, Wt, Gp, DN / nic);
  if (nic > 1)
    greduce_kernel<<<dim3((NROWS * DN + 255) / 256), dim3(256), 0, stream>>>(Gp, G, nic);
  swtab_kernel<<<dim3(NROWS + 2), dim3(64), 0, stream>>>(G, conv_b, score_w, G, SW);
  gbst_main_kernel<<<dim3(BN * NWN), dim3(256), 0, stream>>>(ids, G, SW, conv_b, out);
}

// Round 3
// 97.581 us; speedup vs baseline: 1.4518x; 1.2584x over previous
//
#include <hip/hip_runtime.h>

#define VOCABN 256
#define DN 512
#define MN 4
#define DSN 2
#define KN 5
#define BN 8
#define LN 8192
#define WN 12                     // window positions per block (multiple of lcm(2,3,4)=12)
#define NW12 ((LN + WN - 1) / WN) // 683 windows per batch
#define LOUTN (LN / DSN)          // 4096
#define NROWS (KN * VOCABN)       // 1280 G rows (+1 zero row)
#define ROWB (DN * 4)             // 2048 bytes per G row
#define VPB 16                    // vocab rows per gpart block

// ---------------- kernel 1: repack conv_w [O][I][K] -> Wt [K][I][O] ----------------
__global__ void repack_kernel(const float* __restrict__ cw, float* __restrict__ Wt) {
  int idx = blockIdx.x * 256 + threadIdx.x;
  if (idx < KN * DN * DN) {
    int o = idx % DN;
    int i = (idx / DN) % DN;
    int k = idx / (DN * DN);
    Wt[idx] = cw[(o * DN + i) * KN + k];
  }
}

// ---------------- kernel 2: partial GEMM ----------------
// Gp[ic][k][v][o] = sum_{i in chunk ic} emb[v][i] * Wt[k][i][o]
__global__ __launch_bounds__(512) void gpart_kernel(const float* __restrict__ emb,
                                                    const float* __restrict__ Wt,
                                                    float* __restrict__ Gp, int clen) {
  const int o = threadIdx.x;
  const int vg = blockIdx.x % (VOCABN / VPB);
  const int ic = blockIdx.x / (VOCABN / VPB);
  __shared__ float se[VPB * DN];
  for (int t = threadIdx.x; t < VPB * clen; t += 512) {
    int v = t / clen, i = t % clen;
    se[v * clen + i] = emb[(vg * VPB + v) * DN + ic * clen + i];
  }
  __syncthreads();
  float acc[VPB][KN];
#pragma unroll
  for (int v = 0; v < VPB; ++v)
#pragma unroll
    for (int k = 0; k < KN; ++k) acc[v][k] = 0.f;

  for (int i = 0; i < clen; ++i) {
    const int ig = ic * clen + i;
    float wv[KN];
#pragma unroll
    for (int k = 0; k < KN; ++k) wv[k] = Wt[(k * DN + ig) * DN + o];
#pragma unroll
    for (int v = 0; v < VPB; ++v) {
      const float e = se[v * clen + i];
#pragma unroll
      for (int k = 0; k < KN; ++k) acc[v][k] += e * wv[k];
    }
  }
#pragma unroll
  for (int v = 0; v < VPB; ++v)
#pragma unroll
    for (int k = 0; k < KN; ++k)
      Gp[((size_t)(ic * KN + k) * VOCABN + (vg * VPB + v)) * DN + o] = acc[v][k];
}

// ---------------- kernel 3: reduce partials -> G[k][v][o] (float4) ----------------
__global__ void greduce_kernel(const float4* __restrict__ Gp, float4* __restrict__ G, int nic) {
  int e = blockIdx.x * 256 + threadIdx.x;
  if (e < NROWS * DN / 4) {
    float4 s = Gp[e];
    for (int ic = 1; ic < nic; ++ic) {
      float4 p = Gp[(size_t)ic * (NROWS * DN / 4) + e];
      s.x += p.x; s.y += p.y; s.z += p.z; s.w += p.w;
    }
    G[e] = s;
  }
}

// ---------------- kernel 4: score table SW[row] = G[row]·score_w, zero row, sbias ----------------
__global__ __launch_bounds__(64) void swtab_kernel(const float* __restrict__ G,
                                                   const float* __restrict__ conv_b,
                                                   const float* __restrict__ score_w,
                                                   float* __restrict__ Gz,
                                                   float* __restrict__ SW) {
  const int r = blockIdx.x;
  const int lane = threadIdx.x;
  if (r == NROWS) {
#pragma unroll
    for (int q = 0; q < DN / 64; ++q) Gz[(size_t)NROWS * DN + lane + q * 64] = 0.f;
    if (lane == 0) SW[NROWS] = 0.f;
    return;
  }
  const float* src = (r == NROWS + 1) ? conv_b : (G + (size_t)r * DN);
  float acc = 0.f;
#pragma unroll
  for (int q = 0; q < DN / 64; ++q) acc += src[lane + q * 64] * score_w[lane + q * 64];
#pragma unroll
  for (int off = 32; off > 0; off >>= 1) acc += __shfl_xor(acc, off, 64);
  if (lane == 0) SW[r] = acc;
}

// ---------------- kernel 5: fused GBST main ----------------
// block = (batch, 12-position window), 512 threads, thread <-> channel o (scalar f32)
__global__ __launch_bounds__(512, 6) void gbst_main_kernel(const int* __restrict__ ids,
                                                           const float* __restrict__ G,
                                                           const float* __restrict__ SW,
                                                           const float* __restrict__ conv_b,
                                                           float* __restrict__ out) {
  const int blk = blockIdx.x;
  const int b = blk / NW12;
  const int w = blk % NW12;
  const int l0 = w * WN;
  const int tid = threadIdx.x;

  __shared__ int offs[WN + 4][KN];  // byte offset of G row for tap (j,k)
  __shared__ float t_s[WN];
  __shared__ float4 wm_s[WN];

  // P0: per-tap row byte-offsets (zero row for out-of-range)
  if (tid < (WN + 4) * KN) {
    int j = tid / KN, k = tid % KN;
    int p = l0 + j - 2;
    int row = NROWS;
    if ((unsigned)p < (unsigned)LN) row = k * VOCABN + ids[b * LN + p];
    offs[j][k] = row * ROWB;
  }
  __syncthreads();

  // P1: scalar scores t[s] via SW table (threads 0..11) — issued before the big gather
  if (tid < WN) {
    float tv = SW[NROWS + 1];  // sbias
#pragma unroll
    for (int k = 0; k < KN; ++k) tv += SW[(unsigned)offs[tid + k][k] >> 11];
    t_s[tid] = (l0 + tid < LN) ? tv : 0.f;
  }

  // P2: gather conv outputs y[s] = sum_k G[k][id] (bias+mask applied after)
  const char* Gb = (const char*)G;
  const int laneoff = tid * 4;
  float y[WN];
#pragma unroll
  for (int s = 0; s < WN; ++s) {
    float acc = 0.f;
#pragma unroll
    for (int k = 0; k < KN; ++k)
      acc += *(const float*)(Gb + offs[s + k][k] + laneoff);
    y[s] = acc;
  }
  const float bias = conv_b[tid];
#pragma unroll
  for (int s = 0; s < WN; ++s) y[s] = (l0 + s < LN) ? y[s] + bias : 0.f;
  __syncthreads();

  // P3: per-position softmax over the 4 block-size scores (threads 0..11)
  if (tid < WN && l0 + tid < LN) {
    const int ll = tid;
    float s1 = t_s[ll];
    int j2 = ll & ~1;
    float s2 = 0.5f * (t_s[j2] + t_s[j2 + 1]);
    int j3 = (ll / 3) * 3;
    float s3 = (1.f / 3.f) * (t_s[j3] + t_s[j3 + 1] + t_s[j3 + 2]);
    int j4 = ll & ~3;
    float s4 = 0.25f * (t_s[j4] + t_s[j4 + 1] + t_s[j4 + 2] + t_s[j4 + 3]);
    float mx = fmaxf(fmaxf(s1, s2), fmaxf(s3, s4));
    float e1 = __expf(s1 - mx), e2 = __expf(s2 - mx);
    float e3 = __expf(s3 - mx), e4 = __expf(s4 - mx);
    float inv = 1.f / (e1 + e2 + e3 + e4);
    wm_s[ll] = make_float4(e1 * inv, e2 * inv, e3 * inv, e4 * inv);
  }
  __syncthreads();

  // P4: pool sums (compile-time indices)
  float S2[6], S3[4], S4[3];
#pragma unroll
  for (int j = 0; j < 6; ++j) S2[j] = y[2 * j] + y[2 * j + 1];
#pragma unroll
  for (int j = 0; j < 4; ++j) S3[j] = y[3 * j] + y[3 * j + 1] + y[3 * j + 2];
#pragma unroll
  for (int j = 0; j < 3; ++j) S4[j] = S2[2 * j] + S2[2 * j + 1];

  // P5: latent mix + final /2 downsample, coalesced scalar stores
#pragma unroll
  for (int jo = 0; jo < WN / 2; ++jo) {
    const int orow = (l0 >> 1) + jo;
    if (orow < LOUTN) {
      float acc = 0.f;
#pragma unroll
      for (int dl = 0; dl < 2; ++dl) {
        const int ll = 2 * jo + dl;
        const float4 wv = wm_s[ll];
        acc += wv.x * y[ll] + (wv.y * 0.5f) * S2[jo] + (wv.z * (1.f / 3.f)) * S3[ll / 3] +
               (wv.w * 0.25f) * S4[jo >> 1];
      }
      out[((size_t)b * LOUTN + orow) * DN + tid] = 0.5f * acc;
    }
  }
}

extern "C" void kernel_launch(void* const* d_in, const int* in_sizes, int n_in,
                              void* d_out, int out_size, void* d_ws, size_t ws_size,
                              hipStream_t stream) {
  const int* ids = (const int*)d_in[0];
  const float* emb = (const float*)d_in[1];
  const float* conv_w = (const float*)d_in[2];
  const float* conv_b = (const float*)d_in[3];
  const float* score_w = (const float*)d_in[4];
  float* out = (float*)d_out;

  const size_t WT_BYTES = (size_t)KN * DN * DN * 4;     // 5.24 MB
  const size_t GP_BYTES = (size_t)NROWS * DN * 4;       // 2.62 MB per partial
  const size_t G_BYTES = (size_t)(NROWS + 1) * DN * 4;  // G + zero row
  const size_t SW_BYTES = (size_t)(NROWS + 2) * 4;

  int nic = 8;
  if (ws_size < WT_BYTES + 8 * GP_BYTES + G_BYTES + SW_BYTES) nic = 1;

  char* ws = (char*)d_ws;
  float* Wt = (float*)ws;
  float* Gp = (float*)(ws + WT_BYTES);
  float* G = (float*)(ws + WT_BYTES + (size_t)nic * GP_BYTES);
  if (nic == 1) {
    Gp = (float*)(ws + WT_BYTES);
    G = Gp;  // write directly as final
  }
  float* SW = (float*)((char*)G + G_BYTES);

  repack_kernel<<<dim3((KN * DN * DN + 255) / 256), dim3(256), 0, stream>>>(conv_w, Wt);
  gpart_kernel<<<dim3((VOCABN / VPB) * nic), dim3(512), 0, stream>>>(emb, Wt, Gp, DN / nic);
  if (nic > 1)
    greduce_kernel<<<dim3((NROWS * DN / 4 + 255) / 256), dim3(256), 0, stream>>>(
        (const float4*)Gp, (float4*)G, nic);
  swtab_kernel<<<dim3(NROWS + 2), dim3(64), 0, stream>>>(G, conv_b, score_w, G, SW);
  gbst_main_kernel<<<dim3(BN * NW12), dim3(512), 0, stream>>>(ids, G, SW, conv_b, out);
}

// Round 4
// 75.596 us; speedup vs baseline: 1.8740x; 1.2908x over previous
//
#include <hip/hip_runtime.h>

#define VOCABN 256
#define DN 512
#define DSN 2
#define KN 5
#define BN 8
#define LN 8192
#define WN 12                     // window positions per block (multiple of lcm(2,3,4)=12)
#define NW12 ((LN + WN - 1) / WN) // 683 windows per batch
#define LOUTN (LN / DSN)          // 4096
#define NROWS (KN * VOCABN)       // 1280 G rows (+1 zero row)
#define ROWB (DN * 2)             // 1024 bytes per bf16 G row

__device__ inline unsigned short f2bf(float f) {  // RNE f32->bf16
  unsigned int x = __float_as_uint(f);
  return (unsigned short)((x + 0x7FFFu + ((x >> 16) & 1u)) >> 16);
}
__device__ inline float bf2f(unsigned short u) {
  return __uint_as_float((unsigned int)u << 16);
}

// ---------------- kernel 1: embT[i][v] = emb[v][i] (coalesced LDS transpose) ----------------
__global__ __launch_bounds__(256) void embT_kernel(const float* __restrict__ emb,
                                                   float* __restrict__ embT) {
  __shared__ float t[64][65];
  const int i0 = (blockIdx.x % 8) * 64;
  const int v0 = (blockIdx.x / 8) * 64;
  const int tid = threadIdx.x;
  const int c4 = (tid % 16) * 4;
  const int r = tid / 16;
#pragma unroll
  for (int p = 0; p < 4; ++p) {
    const float4 f = *(const float4*)(emb + (size_t)(v0 + p * 16 + r) * DN + i0 + c4);
    t[p * 16 + r][c4 + 0] = f.x;
    t[p * 16 + r][c4 + 1] = f.y;
    t[p * 16 + r][c4 + 2] = f.z;
    t[p * 16 + r][c4 + 3] = f.w;
  }
  __syncthreads();
#pragma unroll
  for (int p = 0; p < 4; ++p) {
    const int i = p * 16 + r;
    float4 f;
    f.x = t[c4 + 0][i];
    f.y = t[c4 + 1][i];
    f.z = t[c4 + 2][i];
    f.w = t[c4 + 3][i];
    *(float4*)(embT + (size_t)(i0 + i) * VOCABN + v0 + c4) = f;
  }
}

// ---------------- kernel 2: coalesced repack conv_w [O][I][K] -> Wt [K][I][O] ----------------
// block: o-tile 64 x i-chunk 32 (all K). Reads contiguous 160-col runs, writes 256B runs.
__global__ __launch_bounds__(256) void repack_kernel(const float* __restrict__ cw,
                                                     float* __restrict__ Wt) {
  __shared__ float t[64][161];  // [o][i_local*5+k]
  const int o0 = (blockIdx.x % 8) * 64;
  const int i0 = (blockIdx.x / 8) * 32;
  const int tid = threadIdx.x;
  for (int idx = tid; idx < 64 * 160; idx += 256) {
    int o = idx / 160, c = idx % 160;
    t[o][c] = cw[(size_t)(o0 + o) * (DN * KN) + i0 * KN + c];
  }
  __syncthreads();
  for (int widx = tid; widx < KN * 32 * 64; widx += 256) {
    int o = widx % 64;
    int ii = (widx / 64) % 32;
    int k = widx / 2048;
    Wt[((size_t)k * DN + i0 + ii) * DN + o0 + o] = t[o][ii * 5 + k];
  }
}

// ---------------- kernel 3: build GEMM  G[k*256+v][o] = sum_i emb[v][i]*cw[o][i][k] ----------------
// f32 register-tiled, no split-K. grid 160 = 5k x 8 otile x 4 vtile; 256 thr; 4v x 4o per thread.
__global__ __launch_bounds__(256) void gbuild_kernel(const float* __restrict__ embT,
                                                     const float* __restrict__ Wt,
                                                     unsigned short* __restrict__ G) {
  const int bx = blockIdx.x;
  const int vt = bx % 4, ot = (bx / 4) % 8, k = bx / 32;
  const int v0 = vt * 64, o0 = ot * 64;
  const int tid = threadIdx.x;
  const int ox = tid % 16, vx = tid / 16;
  __shared__ float se[32][64];  // [i][v]
  __shared__ float wt[32][64];  // [i][o]
  float acc[4][4] = {};
  const int sr = tid / 16;        // stage row 0..15
  const int sc = (tid % 16) * 4;  // stage col
  for (int ic = 0; ic < 16; ++ic) {
#pragma unroll
    for (int p = 0; p < 2; ++p) {
      const int i = p * 16 + sr;
      *(float4*)&se[i][sc] = *(const float4*)(embT + (size_t)(ic * 32 + i) * VOCABN + v0 + sc);
      *(float4*)&wt[i][sc] = *(const float4*)(Wt + ((size_t)k * DN + ic * 32 + i) * DN + o0 + sc);
    }
    __syncthreads();
#pragma unroll
    for (int i = 0; i < 32; ++i) {
      const float4 a = *(const float4*)&se[i][vx * 4];
      const float4 b = *(const float4*)&wt[i][ox * 4];
      acc[0][0] += a.x * b.x; acc[0][1] += a.x * b.y; acc[0][2] += a.x * b.z; acc[0][3] += a.x * b.w;
      acc[1][0] += a.y * b.x; acc[1][1] += a.y * b.y; acc[1][2] += a.y * b.z; acc[1][3] += a.y * b.w;
      acc[2][0] += a.z * b.x; acc[2][1] += a.z * b.y; acc[2][2] += a.z * b.z; acc[2][3] += a.z * b.w;
      acc[3][0] += a.w * b.x; acc[3][1] += a.w * b.y; acc[3][2] += a.w * b.z; acc[3][3] += a.w * b.w;
    }
    __syncthreads();
  }
#pragma unroll
  for (int vi = 0; vi < 4; ++vi) {
    const int row = k * VOCABN + v0 + vx * 4 + vi;
    ushort4 u;
    u.x = f2bf(acc[vi][0]);
    u.y = f2bf(acc[vi][1]);
    u.z = f2bf(acc[vi][2]);
    u.w = f2bf(acc[vi][3]);
    *(ushort4*)((char*)G + (size_t)row * ROWB + (size_t)(o0 + ox * 4) * 2) = u;
  }
}

// ---------------- kernel 4: score table SW[row] = G[row]·score_w, zero row, sbias ----------------
__global__ __launch_bounds__(64) void swtab_kernel(const unsigned short* __restrict__ G,
                                                   const float* __restrict__ conv_b,
                                                   const float* __restrict__ score_w,
                                                   unsigned short* __restrict__ Gz,
                                                   float* __restrict__ SW) {
  const int r = blockIdx.x;
  const int lane = threadIdx.x;
  if (r == NROWS) {  // zero row (bf16) + SW entry
    ushort4 z;
    z.x = z.y = z.z = z.w = 0;
    *(ushort4*)((char*)Gz + (size_t)NROWS * ROWB + lane * 8) = z;
    *(ushort4*)((char*)Gz + (size_t)NROWS * ROWB + 512 + lane * 8) = z;
    if (lane == 0) SW[NROWS] = 0.f;
    return;
  }
  float acc = 0.f;
  if (r == NROWS + 1) {
#pragma unroll
    for (int q = 0; q < DN / 64; ++q)
      acc += conv_b[lane + q * 64] * score_w[lane + q * 64];
  } else {
#pragma unroll
    for (int q = 0; q < DN / 64; ++q)
      acc += bf2f(G[(size_t)r * DN + lane + q * 64]) * score_w[lane + q * 64];
  }
#pragma unroll
  for (int off = 32; off > 0; off >>= 1) acc += __shfl_xor(acc, off, 64);
  if (lane == 0) SW[r] = acc;
}

// ---------------- kernel 5: fused GBST main (bf16 G gathers) ----------------
__global__ __launch_bounds__(512, 6) void gbst_main_kernel(const int* __restrict__ ids,
                                                           const unsigned short* __restrict__ G,
                                                           const float* __restrict__ SW,
                                                           const float* __restrict__ conv_b,
                                                           float* __restrict__ out) {
  const int blk = blockIdx.x;
  const int b = blk / NW12;
  const int w = blk % NW12;
  const int l0 = w * WN;
  const int tid = threadIdx.x;

  __shared__ int offs[WN + 4][KN];  // byte offset of G row for tap (j,k)
  __shared__ float t_s[WN];
  __shared__ float4 wm_s[WN];

  // P0: per-tap row byte-offsets (zero row for out-of-range)
  if (tid < (WN + 4) * KN) {
    int j = tid / KN, k = tid % KN;
    int p = l0 + j - 2;
    int row = NROWS;
    if ((unsigned)p < (unsigned)LN) row = k * VOCABN + ids[b * LN + p];
    offs[j][k] = row * ROWB;
  }
  __syncthreads();

  // P1: scalar scores t[s] via SW table (threads 0..11)
  if (tid < WN) {
    float tv = SW[NROWS + 1];  // sbias
#pragma unroll
    for (int k = 0; k < KN; ++k) tv += SW[(unsigned)offs[tid + k][k] >> 10];
    t_s[tid] = (l0 + tid < LN) ? tv : 0.f;
  }

  // P2: gather conv outputs y[s] = sum_k G[k][id] (bf16 rows)
  const char* Gb = (const char*)G;
  const int laneoff = tid * 2;
  float y[WN];
#pragma unroll
  for (int s = 0; s < WN; ++s) {
    float acc = 0.f;
#pragma unroll
    for (int k = 0; k < KN; ++k)
      acc += bf2f(*(const unsigned short*)(Gb + offs[s + k][k] + laneoff));
    y[s] = acc;
  }
  const float bias = conv_b[tid];
#pragma unroll
  for (int s = 0; s < WN; ++s) y[s] = (l0 + s < LN) ? y[s] + bias : 0.f;
  __syncthreads();

  // P3: per-position softmax over the 4 block-size scores (threads 0..11)
  if (tid < WN && l0 + tid < LN) {
    const int ll = tid;
    float s1 = t_s[ll];
    int j2 = ll & ~1;
    float s2 = 0.5f * (t_s[j2] + t_s[j2 + 1]);
    int j3 = (ll / 3) * 3;
    float s3 = (1.f / 3.f) * (t_s[j3] + t_s[j3 + 1] + t_s[j3 + 2]);
    int j4 = ll & ~3;
    float s4 = 0.25f * (t_s[j4] + t_s[j4 + 1] + t_s[j4 + 2] + t_s[j4 + 3]);
    float mx = fmaxf(fmaxf(s1, s2), fmaxf(s3, s4));
    float e1 = __expf(s1 - mx), e2 = __expf(s2 - mx);
    float e3 = __expf(s3 - mx), e4 = __expf(s4 - mx);
    float inv = 1.f / (e1 + e2 + e3 + e4);
    wm_s[ll] = make_float4(e1 * inv, e2 * inv, e3 * inv, e4 * inv);
  }
  __syncthreads();

  // P4: pool sums (compile-time indices)
  float S2[6], S3[4], S4[3];
#pragma unroll
  for (int j = 0; j < 6; ++j) S2[j] = y[2 * j] + y[2 * j + 1];
#pragma unroll
  for (int j = 0; j < 4; ++j) S3[j] = y[3 * j] + y[3 * j + 1] + y[3 * j + 2];
#pragma unroll
  for (int j = 0; j < 3; ++j) S4[j] = S2[2 * j] + S2[2 * j + 1];

  // P5: latent mix + final /2 downsample, coalesced scalar stores
#pragma unroll
  for (int jo = 0; jo < WN / 2; ++jo) {
    const int orow = (l0 >> 1) + jo;
    if (orow < LOUTN) {
      float acc = 0.f;
#pragma unroll
      for (int dl = 0; dl < 2; ++dl) {
        const int ll = 2 * jo + dl;
        const float4 wv = wm_s[ll];
        acc += wv.x * y[ll] + (wv.y * 0.5f) * S2[jo] + (wv.z * (1.f / 3.f)) * S3[ll / 3] +
               (wv.w * 0.25f) * S4[jo >> 1];
      }
      out[((size_t)b * LOUTN + orow) * DN + tid] = 0.5f * acc;
    }
  }
}

extern "C" void kernel_launch(void* const* d_in, const int* in_sizes, int n_in,
                              void* d_out, int out_size, void* d_ws, size_t ws_size,
                              hipStream_t stream) {
  const int* ids = (const int*)d_in[0];
  const float* emb = (const float*)d_in[1];
  const float* conv_w = (const float*)d_in[2];
  const float* conv_b = (const float*)d_in[3];
  const float* score_w = (const float*)d_in[4];
  float* out = (float*)d_out;

  char* ws = (char*)d_ws;
  float* embT = (float*)ws;                               // 512*256*4 = 512 KB
  float* Wt = (float*)(ws + 524288);                      // 5*512*512*4 = 5.24 MB
  unsigned short* G = (unsigned short*)(ws + 5767168);    // 1281 rows * 1024 B = 1.31 MB
  float* SW = (float*)(ws + 7079936);                     // 1282 * 4 B

  embT_kernel<<<dim3(32), dim3(256), 0, stream>>>(emb, embT);
  repack_kernel<<<dim3(128), dim3(256), 0, stream>>>(conv_w, Wt);
  gbuild_kernel<<<dim3(160), dim3(256), 0, stream>>>(embT, Wt, G);
  swtab_kernel<<<dim3(NROWS + 2), dim3(64), 0, stream>>>(G, conv_b, score_w, G, SW);
  gbst_main_kernel<<<dim3(BN * NW12), dim3(512), 0, stream>>>(ids, G, SW, conv_b, out);
}

// Round 5
// 66.454 us; speedup vs baseline: 2.1319x; 1.1376x over previous
//
#include <hip/hip_runtime.h>

#define VOCABN 256
#define DN 512
#define DSN 2
#define KN 5
#define BN 8
#define LN 8192
#define WN 12                     // window positions per block (multiple of lcm(2,3,4)=12)
#define NW12 ((LN + WN - 1) / WN) // 683 windows per batch
#define LOUTN (LN / DSN)          // 4096
#define NROWS (KN * VOCABN)       // 1280 G rows (+1 zero row)
#define ROWB (DN * 2)             // 1024 bytes per bf16 G row

__device__ inline unsigned short f2bf(float f) {  // RNE f32->bf16
  unsigned int x = __float_as_uint(f);
  return (unsigned short)((x + 0x7FFFu + ((x >> 16) & 1u)) >> 16);
}

// ---------------- kernel 1: build GEMM  G[k*256+v][o] = sum_i emb[v][i]*conv_w[o][i][k] ----
// Reads emb and conv_w DIRECTLY (no repack kernels). grid 160 = 4vt x 8ot x 5k; 256 thr;
// 4v x 4o per thread, K staged 32 at a time into LDS ([i][v] and [i][o], pad to 68 for
// alignment + bank spread).
__global__ __launch_bounds__(256) void gbuild_kernel(const float* __restrict__ emb,
                                                     const float* __restrict__ cw,
                                                     unsigned short* __restrict__ G) {
  const int bx = blockIdx.x;
  const int vt = bx & 3, ot = (bx >> 2) & 7, k = bx >> 5;
  const int v0 = vt * 64, o0 = ot * 64;
  const int tid = threadIdx.x;
  const int ox = tid & 15, vx = tid >> 4;
  const int c = tid & 31, rr = tid >> 5;  // stage: i-col 0..31, row-group 0..7
  __shared__ float se[32][68];  // [i][v]
  __shared__ float wt[32][68];  // [i][o]
  float acc[4][4] = {};
  for (int ic = 0; ic < 16; ++ic) {
    const int i0 = ic * 32;
    __syncthreads();  // protect previous iter's reads
#pragma unroll
    for (int p = 0; p < 8; ++p) {
      const int q = p * 8 + rr;
      se[c][q] = emb[(size_t)(v0 + q) * DN + i0 + c];                  // coalesced rows
      wt[c][q] = cw[((size_t)(o0 + q) * DN + i0 + c) * KN + k];        // strided, L2-hot
    }
    __syncthreads();
#pragma unroll
    for (int i = 0; i < 32; ++i) {
      const float4 a = *(const float4*)&se[i][vx * 4];
      const float4 b = *(const float4*)&wt[i][ox * 4];
      acc[0][0] += a.x * b.x; acc[0][1] += a.x * b.y; acc[0][2] += a.x * b.z; acc[0][3] += a.x * b.w;
      acc[1][0] += a.y * b.x; acc[1][1] += a.y * b.y; acc[1][2] += a.y * b.z; acc[1][3] += a.y * b.w;
      acc[2][0] += a.z * b.x; acc[2][1] += a.z * b.y; acc[2][2] += a.z * b.z; acc[2][3] += a.z * b.w;
      acc[3][0] += a.w * b.x; acc[3][1] += a.w * b.y; acc[3][2] += a.w * b.z; acc[3][3] += a.w * b.w;
    }
  }
#pragma unroll
  for (int vi = 0; vi < 4; ++vi) {
    const int row = k * VOCABN + v0 + vx * 4 + vi;
    ushort4 u;
    u.x = f2bf(acc[vi][0]);
    u.y = f2bf(acc[vi][1]);
    u.z = f2bf(acc[vi][2]);
    u.w = f2bf(acc[vi][3]);
    *(ushort4*)((char*)G + (size_t)row * ROWB + (size_t)(o0 + ox * 4) * 2) = u;
  }
}

// ---------------- kernel 2: score table SW[row] = G[row]·score_w, zero row, sbias ----------
// One uint4 (8 bf16) load per lane; 64-lane shuffle reduce.
__global__ __launch_bounds__(64) void swtab_kernel(const unsigned short* __restrict__ G,
                                                   const float* __restrict__ conv_b,
                                                   const float* __restrict__ score_w,
                                                   unsigned short* __restrict__ Gz,
                                                   float* __restrict__ SW) {
  const int r = blockIdx.x;
  const int lane = threadIdx.x;
  if (r == NROWS) {  // zero row (bf16) + SW entry
    uint4 z;
    z.x = z.y = z.z = z.w = 0u;
    *(uint4*)((char*)Gz + (size_t)NROWS * ROWB + lane * 16) = z;
    if (lane == 0) SW[NROWS] = 0.f;
    return;
  }
  float acc;
  if (r == NROWS + 1) {  // sbias = conv_b . score_w
    const float4 c0 = *(const float4*)(conv_b + lane * 8);
    const float4 c1 = *(const float4*)(conv_b + lane * 8 + 4);
    const float4 s0 = *(const float4*)(score_w + lane * 8);
    const float4 s1 = *(const float4*)(score_w + lane * 8 + 4);
    acc = c0.x * s0.x + c0.y * s0.y + c0.z * s0.z + c0.w * s0.w +
          c1.x * s1.x + c1.y * s1.y + c1.z * s1.z + c1.w * s1.w;
  } else {
    const uint4 g = *(const uint4*)((const char*)G + (size_t)r * ROWB + lane * 16);
    const float4 s0 = *(const float4*)(score_w + lane * 8);
    const float4 s1 = *(const float4*)(score_w + lane * 8 + 4);
    acc = __uint_as_float(g.x << 16) * s0.x + __uint_as_float(g.x & 0xFFFF0000u) * s0.y +
          __uint_as_float(g.y << 16) * s0.z + __uint_as_float(g.y & 0xFFFF0000u) * s0.w +
          __uint_as_float(g.z << 16) * s1.x + __uint_as_float(g.z & 0xFFFF0000u) * s1.y +
          __uint_as_float(g.w << 16) * s1.z + __uint_as_float(g.w & 0xFFFF0000u) * s1.w;
  }
#pragma unroll
  for (int off = 32; off > 0; off >>= 1) acc += __shfl_xor(acc, off, 64);
  if (lane == 0) SW[r] = acc;
}

// ---------------- kernel 3: fused GBST main ----------------
// block = (batch, 12-position window), 256 threads, thread <-> channel pair; uint gathers
// (2 bf16 per load). Softmax runs entirely on wave 0 (lockstep, no extra barrier).
__global__ __launch_bounds__(256, 5) void gbst_main_kernel(const int* __restrict__ ids,
                                                           const unsigned short* __restrict__ G,
                                                           const float* __restrict__ SW,
                                                           const float* __restrict__ conv_b,
                                                           float* __restrict__ out) {
  const int blk = blockIdx.x;
  const int b = blk / NW12;
  const int w = blk % NW12;
  const int l0 = w * WN;
  const int tid = threadIdx.x;

  __shared__ int offs[WN + 4][KN];  // byte offset of G row for tap (j,k)
  __shared__ float t_s[WN];
  __shared__ float4 wm_s[WN];

  // P0: per-tap row byte-offsets (zero row for out-of-range)
  if (tid < (WN + 4) * KN) {
    int j = tid / KN, kk = tid % KN;
    int p = l0 + j - 2;
    int row = NROWS;
    if ((unsigned)p < (unsigned)LN) row = kk * VOCABN + ids[b * LN + p];
    offs[j][kk] = row * ROWB;
  }
  __syncthreads();

  // P1: issue all gathers (uint = 2 bf16 channels)
  const char* Gb = (const char*)G + tid * 4;
  float2 y[WN];
#pragma unroll
  for (int s = 0; s < WN; ++s) {
    float ax = 0.f, ay = 0.f;
#pragma unroll
    for (int kk = 0; kk < KN; ++kk) {
      const unsigned int g = *(const unsigned int*)(Gb + offs[s + kk][kk]);
      ax += __uint_as_float(g << 16);
      ay += __uint_as_float(g & 0xFFFF0000u);
    }
    y[s].x = ax;
    y[s].y = ay;
  }
  const float2 bias = *(const float2*)(conv_b + tid * 2);
#pragma unroll
  for (int s = 0; s < WN; ++s) {
    const bool valid = (l0 + s) < LN;
    y[s].x = valid ? y[s].x + bias.x : 0.f;
    y[s].y = valid ? y[s].y + bias.y : 0.f;
  }

  // P2 (wave 0 only, lockstep — no barrier needed): scores then softmax
  if (tid < WN) {
    float tv = SW[NROWS + 1];  // sbias
#pragma unroll
    for (int kk = 0; kk < KN; ++kk) tv += SW[(unsigned)offs[tid + kk][kk] >> 10];
    t_s[tid] = (l0 + tid < LN) ? tv : 0.f;
  }
  if (tid < WN && l0 + tid < LN) {
    const int ll = tid;
    float s1 = t_s[ll];
    int j2 = ll & ~1;
    float s2 = 0.5f * (t_s[j2] + t_s[j2 + 1]);
    int j3 = (ll / 3) * 3;
    float s3 = (1.f / 3.f) * (t_s[j3] + t_s[j3 + 1] + t_s[j3 + 2]);
    int j4 = ll & ~3;
    float s4 = 0.25f * (t_s[j4] + t_s[j4 + 1] + t_s[j4 + 2] + t_s[j4 + 3]);
    float mx = fmaxf(fmaxf(s1, s2), fmaxf(s3, s4));
    float e1 = __expf(s1 - mx), e2 = __expf(s2 - mx);
    float e3 = __expf(s3 - mx), e4 = __expf(s4 - mx);
    float inv = 1.f / (e1 + e2 + e3 + e4);
    wm_s[ll] = make_float4(e1 * inv, e2 * inv, e3 * inv, e4 * inv);
  }
  __syncthreads();

  // P3: pool sums (compile-time indices)
  float2 S2[6], S3[4], S4[3];
#pragma unroll
  for (int j = 0; j < 6; ++j) {
    S2[j].x = y[2 * j].x + y[2 * j + 1].x;
    S2[j].y = y[2 * j].y + y[2 * j + 1].y;
  }
#pragma unroll
  for (int j = 0; j < 4; ++j) {
    S3[j].x = y[3 * j].x + y[3 * j + 1].x + y[3 * j + 2].x;
    S3[j].y = y[3 * j].y + y[3 * j + 1].y + y[3 * j + 2].y;
  }
#pragma unroll
  for (int j = 0; j < 3; ++j) {
    S4[j].x = S2[2 * j].x + S2[2 * j + 1].x;
    S4[j].y = S2[2 * j].y + S2[2 * j + 1].y;
  }

  // P4: latent mix + final /2 downsample, coalesced float2 stores
#pragma unroll
  for (int jo = 0; jo < WN / 2; ++jo) {
    const int orow = (l0 >> 1) + jo;
    if (orow < LOUTN) {
      float ax = 0.f, ay = 0.f;
#pragma unroll
      for (int dl = 0; dl < 2; ++dl) {
        const int ll = 2 * jo + dl;
        const float4 wv = wm_s[ll];
        const float c2 = wv.y * 0.5f;
        const float c3 = wv.z * (1.f / 3.f);
        const float c4 = wv.w * 0.25f;
        ax += wv.x * y[ll].x + c2 * S2[jo].x + c3 * S3[ll / 3].x + c4 * S4[jo >> 1].x;
        ay += wv.x * y[ll].y + c2 * S2[jo].y + c3 * S3[ll / 3].y + c4 * S4[jo >> 1].y;
      }
      float2 o2;
      o2.x = 0.5f * ax;
      o2.y = 0.5f * ay;
      *(float2*)(out + ((size_t)b * LOUTN + orow) * DN + tid * 2) = o2;
    }
  }
}

extern "C" void kernel_launch(void* const* d_in, const int* in_sizes, int n_in,
                              void* d_out, int out_size, void* d_ws, size_t ws_size,
                              hipStream_t stream) {
  const int* ids = (const int*)d_in[0];
  const float* emb = (const float*)d_in[1];
  const float* conv_w = (const float*)d_in[2];
  const float* conv_b = (const float*)d_in[3];
  const float* score_w = (const float*)d_in[4];
  float* out = (float*)d_out;

  char* ws = (char*)d_ws;
  unsigned short* G = (unsigned short*)ws;          // 1281 rows * 1024 B = 1.31 MB
  float* SW = (float*)(ws + 1312768);               // 1282 * 4 B

  gbuild_kernel<<<dim3(160), dim3(256), 0, stream>>>(emb, conv_w, G);
  swtab_kernel<<<dim3(NROWS + 2), dim3(64), 0, stream>>>(G, conv_b, score_w, G, SW);
  gbst_main_kernel<<<dim3(BN * NW12), dim3(256), 0, stream>>>(ids, G, SW, conv_b, out);
}

// Round 7
// 51.174 us; speedup vs baseline: 2.7684x; 1.2986x over previous
//
#include <hip/hip_runtime.h>

#define VOCABN 256
#define DN 512
#define DSN 2
#define KN 5
#define BN 8
#define LN 8192
#define WN 12                     // window positions per block (multiple of lcm(2,3,4)=12)
#define NW12 ((LN + WN - 1) / WN) // 683 windows per batch
#define LOUTN (LN / DSN)          // 4096
#define NROWS (KN * VOCABN)       // 1280 G rows (+1 zero row)
#define ROWB (DN * 2)             // 1024 bytes per bf16 G row
#define ISP 4                     // split over i: 4 chunks of 128

__device__ inline unsigned short f2bf(float f) {  // RNE f32->bf16
  unsigned int x = __float_as_uint(f);
  return (unsigned short)((x + 0x7FFFu + ((x >> 16) & 1u)) >> 16);
}

// ---------------- kernel 1: build GEMM partials (round-5-verified core + isp split) ----
// Gp[isp][k*256+v][o] = sum_{i in [isp*128, isp*128+128)} emb[v][i] * conv_w[o][i][k]
// grid 640 = 4vt x 8ot x (5k x 4isp); 256 thr; 4v x 4o per thread; 4 stages of 32 i.
__global__ __launch_bounds__(256) void gbuild_kernel(const float* __restrict__ emb,
                                                     const float* __restrict__ cw,
                                                     float* __restrict__ Gp) {
  const int bx = blockIdx.x;
  const int vt = bx & 3, ot = (bx >> 2) & 7;
  const int kq = bx >> 5;
  const int k = kq % 5, isp = kq / 5;
  const int v0 = vt * 64, o0 = ot * 64;
  const int tid = threadIdx.x;
  const int ox = tid & 15, vx = tid >> 4;
  const int c = tid & 31, rr = tid >> 5;  // stage: i-col 0..31, row-group 0..7
  __shared__ float se[32][68];  // [i][v]
  __shared__ float wt[32][68];  // [i][o]
  float acc[4][4] = {};
  for (int ic = 0; ic < 4; ++ic) {
    const int i0 = isp * 128 + ic * 32;
    __syncthreads();  // protect previous iter's reads
#pragma unroll
    for (int p = 0; p < 8; ++p) {
      const int q = p * 8 + rr;
      se[c][q] = emb[(size_t)(v0 + q) * DN + i0 + c];                  // coalesced rows
      wt[c][q] = cw[((size_t)(o0 + q) * DN + i0 + c) * KN + k];        // strided, L2-hot
    }
    __syncthreads();
#pragma unroll
    for (int i = 0; i < 32; ++i) {
      const float4 a = *(const float4*)&se[i][vx * 4];
      const float4 b = *(const float4*)&wt[i][ox * 4];
      acc[0][0] += a.x * b.x; acc[0][1] += a.x * b.y; acc[0][2] += a.x * b.z; acc[0][3] += a.x * b.w;
      acc[1][0] += a.y * b.x; acc[1][1] += a.y * b.y; acc[1][2] += a.y * b.z; acc[1][3] += a.y * b.w;
      acc[2][0] += a.z * b.x; acc[2][1] += a.z * b.y; acc[2][2] += a.z * b.z; acc[2][3] += a.z * b.w;
      acc[3][0] += a.w * b.x; acc[3][1] += a.w * b.y; acc[3][2] += a.w * b.z; acc[3][3] += a.w * b.w;
    }
  }
#pragma unroll
  for (int vi = 0; vi < 4; ++vi) {
    const int row = k * VOCABN + v0 + vx * 4 + vi;
    float4 f;
    f.x = acc[vi][0];
    f.y = acc[vi][1];
    f.z = acc[vi][2];
    f.w = acc[vi][3];
    *(float4*)(Gp + ((size_t)isp * NROWS + row) * DN + o0 + ox * 4) = f;
  }
}

// ---------------- kernel 2: reduce 4 partials -> bf16 G (elementwise, trivial) ----------
// thread <-> one uint (2 consecutive channels of one row). grid = NROWS*DN/2/256 = 1280.
__global__ __launch_bounds__(256) void greduce_kernel(const float* __restrict__ Gp,
                                                      unsigned int* __restrict__ G32) {
  const int e = blockIdx.x * 256 + threadIdx.x;  // uint index in [0, NROWS*256)
  const int row = e >> 8;                        // 256 uints per 512-ch row
  const int cp = e & 255;                        // uint within row
  float x = 0.f, y = 0.f;
#pragma unroll
  for (int isp = 0; isp < ISP; ++isp) {
    const float2 p = *(const float2*)(Gp + ((size_t)isp * NROWS + row) * DN + cp * 2);
    x += p.x;
    y += p.y;
  }
  G32[e] = (unsigned)f2bf(x) | ((unsigned)f2bf(y) << 16);
}

// ---------------- kernel 3: score table SW[row] = G[row]·score_w, zero row, sbias ----------
// (round-5 verbatim) One uint4 (8 bf16) load per lane; 64-lane shuffle reduce.
__global__ __launch_bounds__(64) void swtab_kernel(const unsigned short* __restrict__ G,
                                                   const float* __restrict__ conv_b,
                                                   const float* __restrict__ score_w,
                                                   unsigned short* __restrict__ Gz,
                                                   float* __restrict__ SW) {
  const int r = blockIdx.x;
  const int lane = threadIdx.x;
  if (r == NROWS) {  // zero row (bf16) + SW entry
    uint4 z;
    z.x = z.y = z.z = z.w = 0u;
    *(uint4*)((char*)Gz + (size_t)NROWS * ROWB + lane * 16) = z;
    if (lane == 0) SW[NROWS] = 0.f;
    return;
  }
  float acc;
  if (r == NROWS + 1) {  // sbias = conv_b . score_w
    const float4 c0 = *(const float4*)(conv_b + lane * 8);
    const float4 c1 = *(const float4*)(conv_b + lane * 8 + 4);
    const float4 s0 = *(const float4*)(score_w + lane * 8);
    const float4 s1 = *(const float4*)(score_w + lane * 8 + 4);
    acc = c0.x * s0.x + c0.y * s0.y + c0.z * s0.z + c0.w * s0.w +
          c1.x * s1.x + c1.y * s1.y + c1.z * s1.z + c1.w * s1.w;
  } else {
    const uint4 g = *(const uint4*)((const char*)G + (size_t)r * ROWB + lane * 16);
    const float4 s0 = *(const float4*)(score_w + lane * 8);
    const float4 s1 = *(const float4*)(score_w + lane * 8 + 4);
    acc = __uint_as_float(g.x << 16) * s0.x + __uint_as_float(g.x & 0xFFFF0000u) * s0.y +
          __uint_as_float(g.y << 16) * s0.z + __uint_as_float(g.y & 0xFFFF0000u) * s0.w +
          __uint_as_float(g.z << 16) * s1.x + __uint_as_float(g.z & 0xFFFF0000u) * s1.y +
          __uint_as_float(g.w << 16) * s1.z + __uint_as_float(g.w & 0xFFFF0000u) * s1.w;
  }
#pragma unroll
  for (int off = 32; off > 0; off >>= 1) acc += __shfl_xor(acc, off, 64);
  if (lane == 0) SW[r] = acc;
}

// ---------------- kernel 4: fused GBST main (round-5 verbatim) ----------------
__global__ __launch_bounds__(256, 5) void gbst_main_kernel(const int* __restrict__ ids,
                                                           const unsigned short* __restrict__ G,
                                                           const float* __restrict__ SW,
                                                           const float* __restrict__ conv_b,
                                                           float* __restrict__ out) {
  const int blk = blockIdx.x;
  const int b = blk / NW12;
  const int w = blk % NW12;
  const int l0 = w * WN;
  const int tid = threadIdx.x;

  __shared__ int offs[WN + 4][KN];  // byte offset of G row for tap (j,k)
  __shared__ float t_s[WN];
  __shared__ float4 wm_s[WN];

  // P0: per-tap row byte-offsets (zero row for out-of-range)
  if (tid < (WN + 4) * KN) {
    int j = tid / KN, kk = tid % KN;
    int p = l0 + j - 2;
    int row = NROWS;
    if ((unsigned)p < (unsigned)LN) row = kk * VOCABN + ids[b * LN + p];
    offs[j][kk] = row * ROWB;
  }
  __syncthreads();

  // P1: issue all gathers (uint = 2 bf16 channels)
  const char* Gb = (const char*)G + tid * 4;
  float2 y[WN];
#pragma unroll
  for (int s = 0; s < WN; ++s) {
    float ax = 0.f, ay = 0.f;
#pragma unroll
    for (int kk = 0; kk < KN; ++kk) {
      const unsigned int g = *(const unsigned int*)(Gb + offs[s + kk][kk]);
      ax += __uint_as_float(g << 16);
      ay += __uint_as_float(g & 0xFFFF0000u);
    }
    y[s].x = ax;
    y[s].y = ay;
  }
  const float2 bias = *(const float2*)(conv_b + tid * 2);
#pragma unroll
  for (int s = 0; s < WN; ++s) {
    const bool valid = (l0 + s) < LN;
    y[s].x = valid ? y[s].x + bias.x : 0.f;
    y[s].y = valid ? y[s].y + bias.y : 0.f;
  }

  // P2 (wave 0 only, lockstep — no barrier needed): scores then softmax
  if (tid < WN) {
    float tv = SW[NROWS + 1];  // sbias
#pragma unroll
    for (int kk = 0; kk < KN; ++kk) tv += SW[(unsigned)offs[tid + kk][kk] >> 10];
    t_s[tid] = (l0 + tid < LN) ? tv : 0.f;
  }
  if (tid < WN && l0 + tid < LN) {
    const int ll = tid;
    float s1 = t_s[ll];
    int j2 = ll & ~1;
    float s2 = 0.5f * (t_s[j2] + t_s[j2 + 1]);
    int j3 = (ll / 3) * 3;
    float s3 = (1.f / 3.f) * (t_s[j3] + t_s[j3 + 1] + t_s[j3 + 2]);
    int j4 = ll & ~3;
    float s4 = 0.25f * (t_s[j4] + t_s[j4 + 1] + t_s[j4 + 2] + t_s[j4 + 3]);
    float mx = fmaxf(fmaxf(s1, s2), fmaxf(s3, s4));
    float e1 = __expf(s1 - mx), e2 = __expf(s2 - mx);
    float e3 = __expf(s3 - mx), e4 = __expf(s4 - mx);
    float inv = 1.f / (e1 + e2 + e3 + e4);
    wm_s[ll] = make_float4(e1 * inv, e2 * inv, e3 * inv, e4 * inv);
  }
  __syncthreads();

  // P3: pool sums (compile-time indices)
  float2 S2[6], S3[4], S4[3];
#pragma unroll
  for (int j = 0; j < 6; ++j) {
    S2[j].x = y[2 * j].x + y[2 * j + 1].x;
    S2[j].y = y[2 * j].y + y[2 * j + 1].y;
  }
#pragma unroll
  for (int j = 0; j < 4; ++j) {
    S3[j].x = y[3 * j].x + y[3 * j + 1].x + y[3 * j + 2].x;
    S3[j].y = y[3 * j].y + y[3 * j + 1].y + y[3 * j + 2].y;
  }
#pragma unroll
  for (int j = 0; j < 3; ++j) {
    S4[j].x = S2[2 * j].x + S2[2 * j + 1].x;
    S4[j].y = S2[2 * j].y + S2[2 * j + 1].y;
  }

  // P4: latent mix + final /2 downsample, coalesced float2 stores
#pragma unroll
  for (int jo = 0; jo < WN / 2; ++jo) {
    const int orow = (l0 >> 1) + jo;
    if (orow < LOUTN) {
      float ax = 0.f, ay = 0.f;
#pragma unroll
      for (int dl = 0; dl < 2; ++dl) {
        const int ll = 2 * jo + dl;
        const float4 wv = wm_s[ll];
        const float c2 = wv.y * 0.5f;
        const float c3 = wv.z * (1.f / 3.f);
        const float c4 = wv.w * 0.25f;
        ax += wv.x * y[ll].x + c2 * S2[jo].x + c3 * S3[ll / 3].x + c4 * S4[jo >> 1].x;
        ay += wv.x * y[ll].y + c2 * S2[jo].y + c3 * S3[ll / 3].y + c4 * S4[jo >> 1].y;
      }
      float2 o2;
      o2.x = 0.5f * ax;
      o2.y = 0.5f * ay;
      *(float2*)(out + ((size_t)b * LOUTN + orow) * DN + tid * 2) = o2;
    }
  }
}

extern "C" void kernel_launch(void* const* d_in, const int* in_sizes, int n_in,
                              void* d_out, int out_size, void* d_ws, size_t ws_size,
                              hipStream_t stream) {
  const int* ids = (const int*)d_in[0];
  const float* emb = (const float*)d_in[1];
  const float* conv_w = (const float*)d_in[2];
  const float* conv_b = (const float*)d_in[3];
  const float* score_w = (const float*)d_in[4];
  float* out = (float*)d_out;

  char* ws = (char*)d_ws;
  float* Gp = (float*)ws;                                 // 4*1280*512*4 = 5,242,880 B
  unsigned short* G = (unsigned short*)(ws + 5242880);    // 1281 rows * 1024 B = 1,311,744
  float* SW = (float*)(ws + 5242880 + 1311744);           // 1282 * 4 B

  gbuild_kernel<<<dim3(640), dim3(256), 0, stream>>>(emb, conv_w, Gp);
  greduce_kernel<<<dim3(NROWS * DN / 2 / 256), dim3(256), 0, stream>>>(Gp, (unsigned int*)G);
  swtab_kernel<<<dim3(NROWS + 2), dim3(64), 0, stream>>>(G, conv_b, score_w, G, SW);
  gbst_main_kernel<<<dim3(BN * NW12), dim3(256), 0, stream>>>(ids, G, SW, conv_b, out);
}

// Round 9
// 49.803 us; speedup vs baseline: 2.8446x; 1.0275x over previous
//
#include <hip/hip_runtime.h>

#define VOCABN 256
#define DN 512
#define DSN 2
#define KN 5
#define BN 8
#define LN 8192
#define WN 12                     // window positions per block (multiple of lcm(2,3,4)=12)
#define NW12 ((LN + WN - 1) / WN) // 683 windows per batch
#define LOUTN (LN / DSN)          // 4096
#define NROWS (KN * VOCABN)       // 1280 G rows (+1 zero row)
#define ROWB (DN * 2)             // 1024 bytes per bf16 G row
#define ISP 4                     // split over i: 4 chunks of 128

// Workspace layout (sizes in BYTES — keep exact):
//   Gp : ISP * NROWS * DN * 4 = 4 * 1280 * 512 * 4 = 10,485,760
//   G  : (NROWS+1) * ROWB     = 1281 * 1024        =  1,311,744
//   SW : (NROWS+2) * 4        =                     5,128
#define GP_BYTES (ISP * NROWS * DN * 4)
#define G_OFF GP_BYTES
#define SW_OFF (G_OFF + (NROWS + 1) * ROWB)

__device__ inline unsigned short f2bf(float f) {  // RNE f32->bf16
  unsigned int x = __float_as_uint(f);
  return (unsigned short)((x + 0x7FFFu + ((x >> 16) & 1u)) >> 16);
}

// ---------------- kernel 1: build GEMM partials (round-7 verbatim) ----------------
// Gp[isp][k*256+v][o] = sum_{i in [isp*128, isp*128+128)} emb[v][i] * conv_w[o][i][k]
// grid 640 = 4vt x 8ot x (5k x 4isp); 256 thr; 4v x 4o per thread; 4 stages of 32 i.
__global__ __launch_bounds__(256) void gbuild_kernel(const float* __restrict__ emb,
                                                     const float* __restrict__ cw,
                                                     float* __restrict__ Gp) {
  const int bx = blockIdx.x;
  const int vt = bx & 3, ot = (bx >> 2) & 7;
  const int kq = bx >> 5;
  const int k = kq % 5, isp = kq / 5;
  const int v0 = vt * 64, o0 = ot * 64;
  const int tid = threadIdx.x;
  const int ox = tid & 15, vx = tid >> 4;
  const int c = tid & 31, rr = tid >> 5;  // stage: i-col 0..31, row-group 0..7
  __shared__ float se[32][68];  // [i][v]
  __shared__ float wt[32][68];  // [i][o]
  float acc[4][4] = {};
  for (int ic = 0; ic < 4; ++ic) {
    const int i0 = isp * 128 + ic * 32;
    __syncthreads();  // protect previous iter's reads
#pragma unroll
    for (int p = 0; p < 8; ++p) {
      const int q = p * 8 + rr;
      se[c][q] = emb[(size_t)(v0 + q) * DN + i0 + c];                  // coalesced rows
      wt[c][q] = cw[((size_t)(o0 + q) * DN + i0 + c) * KN + k];        // strided, L2-hot
    }
    __syncthreads();
#pragma unroll
    for (int i = 0; i < 32; ++i) {
      const float4 a = *(const float4*)&se[i][vx * 4];
      const float4 b = *(const float4*)&wt[i][ox * 4];
      acc[0][0] += a.x * b.x; acc[0][1] += a.x * b.y; acc[0][2] += a.x * b.z; acc[0][3] += a.x * b.w;
      acc[1][0] += a.y * b.x; acc[1][1] += a.y * b.y; acc[1][2] += a.y * b.z; acc[1][3] += a.y * b.w;
      acc[2][0] += a.z * b.x; acc[2][1] += a.z * b.y; acc[2][2] += a.z * b.z; acc[2][3] += a.z * b.w;
      acc[3][0] += a.w * b.x; acc[3][1] += a.w * b.y; acc[3][2] += a.w * b.z; acc[3][3] += a.w * b.w;
    }
  }
#pragma unroll
  for (int vi = 0; vi < 4; ++vi) {
    const int row = k * VOCABN + v0 + vx * 4 + vi;
    float4 f;
    f.x = acc[vi][0];
    f.y = acc[vi][1];
    f.z = acc[vi][2];
    f.w = acc[vi][3];
    *(float4*)(Gp + ((size_t)isp * NROWS + row) * DN + o0 + ox * 4) = f;
  }
}

// ---------------- kernel 2: merged reduce + score table (round-8 logic, fixed layout) ----
// grid NROWS+2 blocks x 256 thr; block r < NROWS owns row r (thread = 2 channels):
// sums ISP partials, writes bf16 row, block-reduces SW[r] from the f32 sums.
// r==NROWS: zero row. r==NROWS+1: sbias.
__global__ __launch_bounds__(256) void gswr_kernel(const float* __restrict__ Gp,
                                                   const float* __restrict__ conv_b,
                                                   const float* __restrict__ score_w,
                                                   unsigned int* __restrict__ G32,
                                                   float* __restrict__ SW) {
  const int r = blockIdx.x;
  const int tid = threadIdx.x;
  __shared__ float sred[4];
  if (r == NROWS) {  // zero row
    G32[(size_t)NROWS * 256 + tid] = 0u;
    if (tid == 0) SW[NROWS] = 0.f;
    return;
  }
  const float2 sw2 = *(const float2*)(score_w + tid * 2);
  float sdot;
  if (r == NROWS + 1) {  // sbias = conv_b . score_w
    const float2 cb2 = *(const float2*)(conv_b + tid * 2);
    sdot = cb2.x * sw2.x + cb2.y * sw2.y;
  } else {
    float x = 0.f, y = 0.f;
#pragma unroll
    for (int isp = 0; isp < ISP; ++isp) {
      const float2 p = *(const float2*)(Gp + ((size_t)isp * NROWS + r) * DN + tid * 2);
      x += p.x;
      y += p.y;
    }
    G32[(size_t)r * 256 + tid] = (unsigned)f2bf(x) | ((unsigned)f2bf(y) << 16);
    sdot = x * sw2.x + y * sw2.y;
  }
#pragma unroll
  for (int off = 32; off > 0; off >>= 1) sdot += __shfl_xor(sdot, off, 64);
  if ((tid & 63) == 0) sred[tid >> 6] = sdot;
  __syncthreads();
  if (tid == 0) SW[r] = sred[0] + sred[1] + sred[2] + sred[3];
}

// ---------------- kernel 3: fused GBST main (round-8 verbatim) ----------
__global__ __launch_bounds__(256, 4) void gbst_main_kernel(const int* __restrict__ ids,
                                                           const unsigned short* __restrict__ G,
                                                           const float* __restrict__ SW,
                                                           const float* __restrict__ conv_b,
                                                           float* __restrict__ out) {
  const int blk = blockIdx.x;
  const int b = blk / NW12;
  const int w = blk % NW12;
  const int l0 = w * WN;
  const int tid = threadIdx.x;

  __shared__ int offs[WN + 4][KN];  // byte offset of G row for tap (j,k)
  __shared__ float t_s[WN];
  __shared__ float4 wm_s[WN];

  // P0: per-tap row byte-offsets (zero row for out-of-range)
  if (tid < (WN + 4) * KN) {
    int j = tid / KN, kk = tid % KN;
    int p = l0 + j - 2;
    int row = NROWS;
    if ((unsigned)p < (unsigned)LN) row = kk * VOCABN + ids[b * LN + p];
    offs[j][kk] = row * ROWB;
  }
  __syncthreads();

  // P1: issue all gathers (uint = 2 bf16 channels)
  const char* Gb = (const char*)G + tid * 4;
  float2 y[WN];
#pragma unroll
  for (int s = 0; s < WN; ++s) {
    float ax = 0.f, ay = 0.f;
#pragma unroll
    for (int kk = 0; kk < KN; ++kk) {
      const unsigned int g = *(const unsigned int*)(Gb + offs[s + kk][kk]);
      ax += __uint_as_float(g << 16);
      ay += __uint_as_float(g & 0xFFFF0000u);
    }
    y[s].x = ax;
    y[s].y = ay;
  }
  const float2 bias = *(const float2*)(conv_b + tid * 2);
#pragma unroll
  for (int s = 0; s < WN; ++s) {
    const bool valid = (l0 + s) < LN;
    y[s].x = valid ? y[s].x + bias.x : 0.f;
    y[s].y = valid ? y[s].y + bias.y : 0.f;
  }

  // P2 (wave 0 only, lockstep — no barrier needed): scores then softmax
  if (tid < WN) {
    float tv = SW[NROWS + 1];  // sbias
#pragma unroll
    for (int kk = 0; kk < KN; ++kk) tv += SW[(unsigned)offs[tid + kk][kk] >> 10];
    t_s[tid] = (l0 + tid < LN) ? tv : 0.f;
  }
  if (tid < WN && l0 + tid < LN) {
    const int ll = tid;
    float s1 = t_s[ll];
    int j2 = ll & ~1;
    float s2 = 0.5f * (t_s[j2] + t_s[j2 + 1]);
    int j3 = (ll / 3) * 3;
    float s3 = (1.f / 3.f) * (t_s[j3] + t_s[j3 + 1] + t_s[j3 + 2]);
    int j4 = ll & ~3;
    float s4 = 0.25f * (t_s[j4] + t_s[j4 + 1] + t_s[j4 + 2] + t_s[j4 + 3]);
    float mx = fmaxf(fmaxf(s1, s2), fmaxf(s3, s4));
    float e1 = __expf(s1 - mx), e2 = __expf(s2 - mx);
    float e3 = __expf(s3 - mx), e4 = __expf(s4 - mx);
    float inv = 1.f / (e1 + e2 + e3 + e4);
    wm_s[ll] = make_float4(e1 * inv, e2 * inv, e3 * inv, e4 * inv);
  }
  __syncthreads();

  // P3: pool sums (compile-time indices)
  float2 S2[6], S3[4], S4[3];
#pragma unroll
  for (int j = 0; j < 6; ++j) {
    S2[j].x = y[2 * j].x + y[2 * j + 1].x;
    S2[j].y = y[2 * j].y + y[2 * j + 1].y;
  }
#pragma unroll
  for (int j = 0; j < 4; ++j) {
    S3[j].x = y[3 * j].x + y[3 * j + 1].x + y[3 * j + 2].x;
    S3[j].y = y[3 * j].y + y[3 * j + 1].y + y[3 * j + 2].y;
  }
#pragma unroll
  for (int j = 0; j < 3; ++j) {
    S4[j].x = S2[2 * j].x + S2[2 * j + 1].x;
    S4[j].y = S2[2 * j].y + S2[2 * j + 1].y;
  }

  // P4: latent mix + final /2 downsample, coalesced float2 stores
#pragma unroll
  for (int jo = 0; jo < WN / 2; ++jo) {
    const int orow = (l0 >> 1) + jo;
    if (orow < LOUTN) {
      float ax = 0.f, ay = 0.f;
#pragma unroll
      for (int dl = 0; dl < 2; ++dl) {
        const int ll = 2 * jo + dl;
        const float4 wv = wm_s[ll];
        const float c2 = wv.y * 0.5f;
        const float c3 = wv.z * (1.f / 3.f);
        const float c4 = wv.w * 0.25f;
        ax += wv.x * y[ll].x + c2 * S2[jo].x + c3 * S3[ll / 3].x + c4 * S4[jo >> 1].x;
        ay += wv.x * y[ll].y + c2 * S2[jo].y + c3 * S3[ll / 3].y + c4 * S4[jo >> 1].y;
      }
      float2 o2;
      o2.x = 0.5f * ax;
      o2.y = 0.5f * ay;
      *(float2*)(out + ((size_t)b * LOUTN + orow) * DN + tid * 2) = o2;
    }
  }
}

extern "C" void kernel_launch(void* const* d_in, const int* in_sizes, int n_in,
                              void* d_out, int out_size, void* d_ws, size_t ws_size,
                              hipStream_t stream) {
  const int* ids = (const int*)d_in[0];
  const float* emb = (const float*)d_in[1];
  const float* conv_w = (const float*)d_in[2];
  const float* conv_b = (const float*)d_in[3];
  const float* score_w = (const float*)d_in[4];
  float* out = (float*)d_out;

  char* ws = (char*)d_ws;
  float* Gp = (float*)ws;                          // 10,485,760 B (4 partials, FIXED size)
  unsigned short* G = (unsigned short*)(ws + G_OFF);   // 1,311,744 B, starts at 10,485,760
  float* SW = (float*)(ws + SW_OFF);               // 5,128 B, starts at 11,797,504

  gbuild_kernel<<<dim3(640), dim3(256), 0, stream>>>(emb, conv_w, Gp);
  gswr_kernel<<<dim3(NROWS + 2), dim3(256), 0, stream>>>(Gp, conv_b, score_w,
                                                         (unsigned int*)G, SW);
  gbst_main_kernel<<<dim3(BN * NW12), dim3(256), 0, stream>>>(ids, G, SW, conv_b, out);
}

// Round 11
// 49.474 us; speedup vs baseline: 2.8635x; 1.0066x over previous
//
#include <hip/hip_runtime.h>

#define VOCABN 256
#define DN 512
#define DSN 2
#define KN 5
#define BN 8
#define LN 8192
#define WN 12                     // window positions per block (multiple of lcm(2,3,4)=12)
#define NW12 ((LN + WN - 1) / WN) // 683 windows per batch
#define LOUTN (LN / DSN)          // 4096
#define NROWS (KN * VOCABN)       // 1280 G rows
#define ROWB (DN * 2)             // 1024 bytes per bf16 G row
#define KPLANE (VOCABN * ROWB)    // 262144 bytes per k-plane
#define ZOFFB (NROWS * ROWB)      // invalid-tap base: rows 1280+q*256 are zero rows
#define SBIAS_IDX (NROWS + 4 * VOCABN + 1)  // 2305
#define ISP 4                     // split over i: 4 chunks of 128

// Workspace layout (BYTES):
//   Gp : ISP * NROWS * DN * 4            = 10,485,760
//   G  : 2305 rows * ROWB                =  2,360,320   (rows 1280+q*256 zeroed, q=0..4)
//   SW : 2306 * 4                        =      9,224
#define GP_BYTES (ISP * NROWS * DN * 4)
#define G_OFF GP_BYTES
#define SW_OFF (G_OFF + 2305 * ROWB)

typedef float nf2 __attribute__((ext_vector_type(2)));  // clang vector for nontemporal store

__device__ inline unsigned short f2bf(float f) {  // RNE f32->bf16
  unsigned int x = __float_as_uint(f);
  return (unsigned short)((x + 0x7FFFu + ((x >> 16) & 1u)) >> 16);
}

// ---------------- kernel 1: build GEMM partials (round-7 verbatim) ----------------
__global__ __launch_bounds__(256) void gbuild_kernel(const float* __restrict__ emb,
                                                     const float* __restrict__ cw,
                                                     float* __restrict__ Gp) {
  const int bx = blockIdx.x;
  const int vt = bx & 3, ot = (bx >> 2) & 7;
  const int kq = bx >> 5;
  const int k = kq % 5, isp = kq / 5;
  const int v0 = vt * 64, o0 = ot * 64;
  const int tid = threadIdx.x;
  const int ox = tid & 15, vx = tid >> 4;
  const int c = tid & 31, rr = tid >> 5;  // stage: i-col 0..31, row-group 0..7
  __shared__ float se[32][68];  // [i][v]
  __shared__ float wt[32][68];  // [i][o]
  float acc[4][4] = {};
  for (int ic = 0; ic < 4; ++ic) {
    const int i0 = isp * 128 + ic * 32;
    __syncthreads();  // protect previous iter's reads
#pragma unroll
    for (int p = 0; p < 8; ++p) {
      const int q = p * 8 + rr;
      se[c][q] = emb[(size_t)(v0 + q) * DN + i0 + c];                  // coalesced rows
      wt[c][q] = cw[((size_t)(o0 + q) * DN + i0 + c) * KN + k];        // strided, L2-hot
    }
    __syncthreads();
#pragma unroll
    for (int i = 0; i < 32; ++i) {
      const float4 a = *(const float4*)&se[i][vx * 4];
      const float4 b = *(const float4*)&wt[i][ox * 4];
      acc[0][0] += a.x * b.x; acc[0][1] += a.x * b.y; acc[0][2] += a.x * b.z; acc[0][3] += a.x * b.w;
      acc[1][0] += a.y * b.x; acc[1][1] += a.y * b.y; acc[1][2] += a.y * b.z; acc[1][3] += a.y * b.w;
      acc[2][0] += a.z * b.x; acc[2][1] += a.z * b.y; acc[2][2] += a.z * b.z; acc[2][3] += a.z * b.w;
      acc[3][0] += a.w * b.x; acc[3][1] += a.w * b.y; acc[3][2] += a.w * b.z; acc[3][3] += a.w * b.w;
    }
  }
#pragma unroll
  for (int vi = 0; vi < 4; ++vi) {
    const int row = k * VOCABN + v0 + vx * 4 + vi;
    float4 f;
    f.x = acc[vi][0];
    f.y = acc[vi][1];
    f.z = acc[vi][2];
    f.w = acc[vi][3];
    *(float4*)(Gp + ((size_t)isp * NROWS + row) * DN + o0 + ox * 4) = f;
  }
}

// ---------------- kernel 2: merged reduce + score table ----------------
// grid NROWS+6 x 256 thr.
//   r < NROWS      : sum ISP partials, write bf16 row, SW[r] = row . score_w
//   NROWS..NROWS+4 : zero G row (NROWS + (r-NROWS)*VOCABN) and its SW slot
//   NROWS+5        : sbias -> SW[SBIAS_IDX]
__global__ __launch_bounds__(256) void gswr_kernel(const float* __restrict__ Gp,
                                                   const float* __restrict__ conv_b,
                                                   const float* __restrict__ score_w,
                                                   unsigned int* __restrict__ G32,
                                                   float* __restrict__ SW) {
  const int r = blockIdx.x;
  const int tid = threadIdx.x;
  __shared__ float sred[4];
  if (r >= NROWS && r < NROWS + 5) {  // zero rows
    const int z = NROWS + (r - NROWS) * VOCABN;
    G32[(size_t)z * 256 + tid] = 0u;
    if (tid == 0) SW[z] = 0.f;
    return;
  }
  const float2 sw2 = *(const float2*)(score_w + tid * 2);
  float sdot;
  if (r == NROWS + 5) {  // sbias = conv_b . score_w
    const float2 cb2 = *(const float2*)(conv_b + tid * 2);
    sdot = cb2.x * sw2.x + cb2.y * sw2.y;
  } else {
    float x = 0.f, y = 0.f;
#pragma unroll
    for (int isp = 0; isp < ISP; ++isp) {
      const float2 p = *(const float2*)(Gp + ((size_t)isp * NROWS + r) * DN + tid * 2);
      x += p.x;
      y += p.y;
    }
    G32[(size_t)r * 256 + tid] = (unsigned)f2bf(x) | ((unsigned)f2bf(y) << 16);
    sdot = x * sw2.x + y * sw2.y;
  }
#pragma unroll
  for (int off = 32; off > 0; off >>= 1) sdot += __shfl_xor(sdot, off, 64);
  if ((tid & 63) == 0) sred[tid >> 6] = sdot;
  __syncthreads();
  if (tid == 0) {
    const float v = sred[0] + sred[1] + sred[2] + sred[3];
    if (r == NROWS + 5) SW[SBIAS_IDX] = v;
    else SW[r] = v;
  }
}

// ---------------- kernel 3: fused GBST main (scalar-addressed gathers) ----------------
// block = (batch, 12-position window), 256 threads, thread <-> channel pair.
// All gather addresses are block-uniform -> SGPR bases, tid*4 voffset.
__global__ __launch_bounds__(256, 5) void gbst_main_kernel(const int* __restrict__ ids,
                                                           const unsigned short* __restrict__ G,
                                                           const float* __restrict__ SW,
                                                           const float* __restrict__ conv_b,
                                                           float* __restrict__ out) {
  const int blk = blockIdx.x;
  const int b = blk / NW12;
  const int w = blk % NW12;
  const int l0 = w * WN;
  const int tid = threadIdx.x;

  __shared__ float t_s[WN];
  __shared__ float4 wm_s[WN];

  // P0: block-uniform tap byte-offsets (compiler emits s_load + scalar ALU)
  int joff[WN + 4];
#pragma unroll
  for (int j = 0; j < WN + 4; ++j) {
    const int p = l0 + j - 2;
    const bool v = ((unsigned)p < (unsigned)LN);
    const int a = v ? (b * LN + p) : 0;
    const int id = ids[a];
    joff[j] = v ? (id * ROWB) : ZOFFB;
  }

  // P1: gathers (uint = 2 bf16 channels); scalar base + tid voffset
  const char* Gc = (const char*)G;
  float2 y[WN];
#pragma unroll
  for (int s = 0; s < WN; ++s) {
    float ax = 0.f, ay = 0.f;
#pragma unroll
    for (int kk = 0; kk < KN; ++kk) {
      const unsigned g = ((const unsigned*)(Gc + (joff[s + kk] + kk * KPLANE)))[tid];
      ax += __uint_as_float(g << 16);
      ay += __uint_as_float(g & 0xFFFF0000u);
    }
    y[s].x = ax;
    y[s].y = ay;
  }
  const float2 bias = *(const float2*)(conv_b + tid * 2);
#pragma unroll
  for (int s = 0; s < WN; ++s) {
    const bool valid = (l0 + s) < LN;  // block-uniform
    y[s].x = valid ? y[s].x + bias.x : 0.f;
    y[s].y = valid ? y[s].y + bias.y : 0.f;
  }

  // P2 (wave 0 only): scalar-loaded scores, then softmax (round-5 math)
  if (tid < 64) {
    const float sbias = SW[SBIAS_IDX];
    float t[WN];
#pragma unroll
    for (int s = 0; s < WN; ++s) {
      float tv = sbias;
#pragma unroll
      for (int kk = 0; kk < KN; ++kk) tv += SW[(joff[s + kk] >> 10) + kk * VOCABN];
      t[s] = (l0 + s < LN) ? tv : 0.f;
    }
    if (tid == 0) {
#pragma unroll
      for (int s = 0; s < WN; ++s) t_s[s] = t[s];  // compile-time indices only
    }
    if (tid < WN && l0 + tid < LN) {
      const int ll = tid;
      float s1 = t_s[ll];
      int j2 = ll & ~1;
      float s2 = 0.5f * (t_s[j2] + t_s[j2 + 1]);
      int j3 = (ll / 3) * 3;
      float s3 = (1.f / 3.f) * (t_s[j3] + t_s[j3 + 1] + t_s[j3 + 2]);
      int j4 = ll & ~3;
      float s4 = 0.25f * (t_s[j4] + t_s[j4 + 1] + t_s[j4 + 2] + t_s[j4 + 3]);
      float mx = fmaxf(fmaxf(s1, s2), fmaxf(s3, s4));
      float e1 = __expf(s1 - mx), e2 = __expf(s2 - mx);
      float e3 = __expf(s3 - mx), e4 = __expf(s4 - mx);
      float inv = 1.f / (e1 + e2 + e3 + e4);
      wm_s[ll] = make_float4(e1 * inv, e2 * inv, e3 * inv, e4 * inv);
    }
  }

  // P3: pool sums (before barrier — waves 1-3 overlap wave 0's softmax)
  float2 S2[6], S3[4], S4[3];
#pragma unroll
  for (int j = 0; j < 6; ++j) {
    S2[j].x = y[2 * j].x + y[2 * j + 1].x;
    S2[j].y = y[2 * j].y + y[2 * j + 1].y;
  }
#pragma unroll
  for (int j = 0; j < 4; ++j) {
    S3[j].x = y[3 * j].x + y[3 * j + 1].x + y[3 * j + 2].x;
    S3[j].y = y[3 * j].y + y[3 * j + 1].y + y[3 * j + 2].y;
  }
#pragma unroll
  for (int j = 0; j < 3; ++j) {
    S4[j].x = S2[2 * j].x + S2[2 * j + 1].x;
    S4[j].y = S2[2 * j].y + S2[2 * j + 1].y;
  }
  __syncthreads();

  // P4: latent mix + final /2 downsample, nontemporal clang-vector stores
#pragma unroll
  for (int jo = 0; jo < WN / 2; ++jo) {
    const int orow = (l0 >> 1) + jo;
    if (orow < LOUTN) {
      float ax = 0.f, ay = 0.f;
#pragma unroll
      for (int dl = 0; dl < 2; ++dl) {
        const int ll = 2 * jo + dl;
        const float4 wv = wm_s[ll];
        const float c2 = wv.y * 0.5f;
        const float c3 = wv.z * (1.f / 3.f);
        const float c4 = wv.w * 0.25f;
        ax += wv.x * y[ll].x + c2 * S2[jo].x + c3 * S3[ll / 3].x + c4 * S4[jo >> 1].x;
        ay += wv.x * y[ll].y + c2 * S2[jo].y + c3 * S3[ll / 3].y + c4 * S4[jo >> 1].y;
      }
      nf2 o2;
      o2.x = 0.5f * ax;
      o2.y = 0.5f * ay;
      __builtin_nontemporal_store(o2, (nf2*)(out + ((size_t)b * LOUTN + orow) * DN + tid * 2));
    }
  }
}

extern "C" void kernel_launch(void* const* d_in, const int* in_sizes, int n_in,
                              void* d_out, int out_size, void* d_ws, size_t ws_size,
                              hipStream_t stream) {
  const int* ids = (const int*)d_in[0];
  const float* emb = (const float*)d_in[1];
  const float* conv_w = (const float*)d_in[2];
  const float* conv_b = (const float*)d_in[3];
  const float* score_w = (const float*)d_in[4];
  float* out = (float*)d_out;

  char* ws = (char*)d_ws;
  float* Gp = (float*)ws;                               // 10,485,760 B
  unsigned short* G = (unsigned short*)(ws + G_OFF);    // 2,360,320 B @ 10,485,760
  float* SW = (float*)(ws + SW_OFF);                    // 9,224 B @ 12,846,080

  gbuild_kernel<<<dim3(640), dim3(256), 0, stream>>>(emb, conv_w, Gp);
  gswr_kernel<<<dim3(NROWS + 6), dim3(256), 0, stream>>>(Gp, conv_b, score_w,
                                                         (unsigned int*)G, SW);
  gbst_main_kernel<<<dim3(BN * NW12), dim3(256), 0, stream>>>(ids, G, SW, conv_b, out);
}